// Round 3
// baseline (3073.808 us; speedup 1.0000x reference)
//
#include <hip/hip_runtime.h>

// Problem: B=512, T=128, I=128, H=512 (fp32 in/out; bf16 MFMA internally)
#define HD 512
#define KD 640
#define G4 2048

typedef short short8 __attribute__((ext_vector_type(8)));
typedef __bf16 bf16x8 __attribute__((ext_vector_type(8)));
typedef float floatx4 __attribute__((ext_vector_type(4)));

static __device__ __forceinline__ unsigned short f2bf(float f) {
  unsigned int u = __float_as_uint(f);
  u += 0x7fffu + ((u >> 16) & 1u);   // RNE
  return (unsigned short)(u >> 16);
}
static __device__ __forceinline__ float sigmoidf_(float x) {
  return 1.f / (1.f + __expf(-x));
}
static __device__ __forceinline__ float tanhf_(float x) {
  float ax = fabsf(x);
  float e = __expf(-2.f * ax);
  float r = 1.f - 2.f * e / (1.f + e);
  return copysignf(r, x);
}

// ---------------- transpose + cast: src[R][C] fp32 -> dst[C][R] bf16
__global__ __launch_bounds__(256) void transpose_f32_bf16(
    const float* __restrict__ src, unsigned short* __restrict__ dst,
    int R, int C) {
  __shared__ unsigned short tile[64][80];
  int nR = R >> 6;
  int tr = blockIdx.x % nR;
  int tc = blockIdx.x / nR;
  int tid = threadIdx.x;
#pragma unroll
  for (int i = 0; i < 2; ++i) {
    int seg = tid + i * 256;
    int row = seg >> 3, ks8 = (seg & 7) * 8;
    const float* p = src + (size_t)(tr * 64 + row) * C + tc * 64 + ks8;
    short8 v;
#pragma unroll
    for (int q = 0; q < 8; ++q) v[q] = (short)f2bf(p[q]);
    *(short8*)(&tile[row][ks8]) = v;
  }
  __syncthreads();
#pragma unroll
  for (int i = 0; i < 2; ++i) {
    int seg = tid + i * 256;
    int cl = seg >> 3, rs8 = (seg & 7) * 8;
    short8 v;
#pragma unroll
    for (int q = 0; q < 8; ++q) v[q] = (short)tile[rs8 + q][cl];
    *(short8*)(dst + (size_t)(tc * 64 + cl) * R + tr * 64 + rs8) = v;
  }
}

// ---------------- x convert: x[b][t][i] fp32 -> xT[t][b][i] bf16
// grid 1024 = t(128) x bchunk(4) x which(2)
__global__ __launch_bounds__(256) void xconv(
    const float* __restrict__ xs, const float* __restrict__ xl,
    unsigned short* __restrict__ xTs, unsigned short* __restrict__ xTl) {
  int t = blockIdx.x & 127;
  int bc = (blockIdx.x >> 7) & 3;
  int which = blockIdx.x >> 9;
  const float* x = which ? xl : xs;
  unsigned short* xT = which ? xTl : xTs;
  int b0 = bc * 128;
#pragma unroll
  for (int i = 0; i < 8; ++i) {
    int seg = threadIdx.x + i * 256;      // 0..2047 = 128 b x 16 i-slots
    int bl_ = seg >> 4, i8 = (seg & 15) * 8;
    const float* p = x + (size_t)(b0 + bl_) * 16384 + t * 128 + i8;
    short8 v;
#pragma unroll
    for (int q = 0; q < 8; ++q) v[q] = (short)f2bf(p[q]);
    *(short8*)(xT + ((size_t)t * 512 + b0 + bl_) * 128 + i8) = v;
  }
}

// ---------------- persistent dual-LSTM over all 128 steps
// grid 256 = lstm(2) x mb(4) x nb(32); block 256 thr = 4 waves (2m x 2n)
// block tile: M=128 b-rows, N=64 (4 gates x 16 h), K=640; B weights in VGPRs
__global__ __launch_bounds__(256, 1) void lstm_persistent(
    const unsigned short* __restrict__ xTs, const unsigned short* __restrict__ xTl,
    const unsigned short* __restrict__ WTs, const unsigned short* __restrict__ WTl,
    const float* __restrict__ bs, const float* __restrict__ bl,
    unsigned short* __restrict__ hs0, unsigned short* __restrict__ hs1,
    unsigned short* __restrict__ hl0, unsigned short* __restrict__ hl1,
    int* __restrict__ bar) {
  const int bid = blockIdx.x;
  const int lstm = bid & 1;
  const int mb = (bid >> 1) & 3;
  const int nb = bid >> 3;
  const int grp = lstm * 4 + mb;
  const int b0 = mb * 128;

  const unsigned short* xT = lstm ? xTl : xTs;
  const unsigned short* WT = lstm ? WTl : WTs;
  const float* bias = lstm ? bl : bs;
  unsigned short* h0 = lstm ? hl0 : hs0;
  unsigned short* h1 = lstm ? hl1 : hs1;

  // LDS: As dbuf [2][128][72]us (36864 B) ; g_lds [4][128][16]f32 (32768 B, ALIASES As)
  //      c_lds [128][16]f32 at 36864 ; bias_lds [4][16]f32 at 45056 ; total 45312 B
  __shared__ unsigned long long smem_[45312 / 8];
  unsigned short* As = (unsigned short*)smem_;
  float* g_lds = (float*)smem_;
  float* c_lds = (float*)((char*)smem_ + 36864);
  float* bias_lds = (float*)((char*)smem_ + 45056);

  const int tid = threadIdx.x;
  const int wave = tid >> 6;
  const int lane = tid & 63;
  const int quad = lane >> 4;
  const int lrow = lane & 15;
  const int wm = wave & 1;   // m half (64 rows)
  const int wn = wave >> 1;  // n half (2 gates)

  if (tid < 64) {
    int g = tid >> 4, hl = tid & 15;
    bias_lds[g * 16 + hl] = bias[g * 512 + nb * 16 + hl];
  }

  // B fragments in registers: breg[nt][kc], nt=gate pair member, kc=K/32 chunk
  bf16x8 breg[2][20];
#pragma unroll
  for (int nt = 0; nt < 2; ++nt) {
    int wrow = (wn * 2 + nt) * 512 + nb * 16 + lrow;
    const unsigned short* wp = WT + (size_t)wrow * KD + quad * 8;
#pragma unroll
    for (int kc = 0; kc < 20; ++kc)
      breg[nt][kc] = __builtin_bit_cast(bf16x8, *(const short8*)(wp + kc * 32));
  }

  // staging helpers: chunk c covers k [c*64, c*64+64)
  auto stageX = [&](int c, int t) {  // c in {0,1}: k < 128 -> x
#pragma unroll
    for (int i = 0; i < 4; ++i) {
      int seg = tid + i * 256;
      int row = seg >> 3, ks8 = (seg & 7) * 8;
      short8 v = *(const short8*)(xT + ((size_t)t * 512 + b0 + row) * 128 + c * 64 + ks8);
      *(short8*)(As + ((size_t)(c & 1) * 128 + row) * 72 + ks8) = v;
    }
  };
  auto stageH = [&](int c, int t, const unsigned short* hr) {  // c in 2..9
#pragma unroll
    for (int i = 0; i < 4; ++i) {
      int seg = tid + i * 256;
      int row = seg >> 3, ks8 = (seg & 7) * 8;
      int kh = c * 64 - 128 + ks8;
      short8 v;
      if (t > 0) v = *(const short8*)(hr + (size_t)(b0 + row) * 512 + kh);
      else       v = (short8){0, 0, 0, 0, 0, 0, 0, 0};
      *(short8*)(As + ((size_t)(c & 1) * 128 + row) * 72 + ks8) = v;
    }
  };

  stageX(0, 0);

#pragma unroll 1
  for (int t = 0; t < 128; ++t) {
    const unsigned short* hr = (t & 1) ? h1 : h0;
    unsigned short* hw = (t & 1) ? h0 : h1;

    floatx4 acc[4][2];
#pragma unroll
    for (int mt = 0; mt < 4; ++mt)
#pragma unroll
      for (int nt = 0; nt < 2; ++nt) acc[mt][nt] = (floatx4){0.f, 0.f, 0.f, 0.f};

#pragma unroll
    for (int c = 0; c < 10; ++c) {
      __syncthreads();   // staging of chunk c complete; prev reads of other buf done
      if (c < 9) {
        if (c + 1 == 1) stageX(1, t);
        else            stageH(c + 1, t, hr);
      }
#pragma unroll
      for (int ks = 0; ks < 2; ++ks) {
        int kq = ks * 32 + quad * 8;
        bf16x8 a[4];
#pragma unroll
        for (int mt = 0; mt < 4; ++mt)
          a[mt] = __builtin_bit_cast(bf16x8,
              *(const short8*)(As + ((size_t)(c & 1) * 128 + wm * 64 + mt * 16 + lrow) * 72 + kq));
#pragma unroll
        for (int mt = 0; mt < 4; ++mt)
#pragma unroll
          for (int nt = 0; nt < 2; ++nt)
            acc[mt][nt] = __builtin_amdgcn_mfma_f32_16x16x32_bf16(
                a[mt], breg[nt][c * 2 + ks], acc[mt][nt], 0, 0, 0);
      }
    }

    __syncthreads();  // all MFMA reads of As done before g_lds (alias) writes
    // scatter pre-activations: g_lds[gate][b_local][h_local]
#pragma unroll
    for (int mt = 0; mt < 4; ++mt)
#pragma unroll
      for (int nt = 0; nt < 2; ++nt)
#pragma unroll
        for (int r = 0; r < 4; ++r)
          g_lds[((wn * 2 + nt) * 128 + (wm * 64 + mt * 16 + quad * 4 + r)) * 16 + lrow] =
              acc[mt][nt][r];
    __syncthreads();

    // gate math: thread handles b=tid>>1, h_local = (tid&1)*8 .. +8
    {
      int b = tid >> 1, h8 = (tid & 1) * 8;
      floatx4 gv[4][2];
#pragma unroll
      for (int g = 0; g < 4; ++g) {
        gv[g][0] = *(floatx4*)(g_lds + ((size_t)g * 128 + b) * 16 + h8);
        gv[g][1] = *(floatx4*)(g_lds + ((size_t)g * 128 + b) * 16 + h8 + 4);
      }
      floatx4 cold[2];
      if (t > 0) {
        cold[0] = *(floatx4*)(c_lds + (size_t)b * 16 + h8);
        cold[1] = *(floatx4*)(c_lds + (size_t)b * 16 + h8 + 4);
      } else {
        cold[0] = (floatx4){0.f, 0.f, 0.f, 0.f};
        cold[1] = (floatx4){0.f, 0.f, 0.f, 0.f};
      }
      floatx4 cnew[2];
      short8 hv;
#pragma unroll
      for (int j = 0; j < 8; ++j) {
        int hi_ = j >> 2, lo_ = j & 3;
        float fg = gv[0][hi_][lo_] + bias_lds[0 * 16 + h8 + j];
        float ig = gv[1][hi_][lo_] + bias_lds[1 * 16 + h8 + j];
        float og = gv[2][hi_][lo_] + bias_lds[2 * 16 + h8 + j];
        float cg = gv[3][hi_][lo_] + bias_lds[3 * 16 + h8 + j];
        float cn = sigmoidf_(fg) * cold[hi_][lo_] + sigmoidf_(ig) * tanhf_(cg);
        float hn = sigmoidf_(og) * tanhf_(cn);
        cnew[hi_][lo_] = cn;
        hv[j] = (short)f2bf(hn);
      }
      *(floatx4*)(c_lds + (size_t)b * 16 + h8) = cnew[0];
      *(floatx4*)(c_lds + (size_t)b * 16 + h8 + 4) = cnew[1];
      *(short8*)(hw + (size_t)(b0 + b) * 512 + nb * 16 + h8) = hv;
    }
    __syncthreads();  // g_lds reads done before next staging clobbers alias

    if (t < 127) {
      stageX(0, t + 1);  // x-part of next step needs no barrier
      // group barrier: 32 blocks sharing (lstm, mb) — h exchange
      __syncthreads();   // all threads' h stores drained (vmcnt) per-wave
      if (tid == 0) {
        __threadfence();                       // release: wb this XCD's L2
        atomicAdd(bar + grp, 1);
        while (__hip_atomic_load(bar + grp, __ATOMIC_RELAXED,
                                 __HIP_MEMORY_SCOPE_AGENT) < 32 * (t + 1))
          __builtin_amdgcn_s_sleep(4);
        __threadfence();                       // acquire: inv stale L2 lines
      }
      __syncthreads();
    }
  }
}

// ---------------- out = tanh(concat(hs,hl) @ out_W + out_b), fp32 out
__global__ __launch_bounds__(256) void out_gemm(
    const unsigned short* __restrict__ hs, const unsigned short* __restrict__ hl,
    const unsigned short* __restrict__ WTo,  // [512][1024] bf16
    const float* __restrict__ ob, float* __restrict__ out) {
  const int bx = blockIdx.x;
  const int mb = bx & 7;
  const int nb = bx >> 3;

  __shared__ unsigned short As2[64][88];
  __shared__ unsigned short Bs2[128][88];

  const int tid = threadIdx.x;
  const int wave = tid >> 6;
  const int lane = tid & 63;
  const int quad = lane >> 4;
  const int lrow = lane & 15;
  const int wm = wave & 1;
  const int wn = wave >> 1;

  floatx4 acc[8];
#pragma unroll
  for (int i = 0; i < 8; ++i) acc[i] = (floatx4){0.f, 0.f, 0.f, 0.f};

  for (int k0 = 0; k0 < 1024; k0 += 64) {
#pragma unroll
    for (int i = 0; i < 2; ++i) {
      int seg = tid + i * 256;
      int row = seg >> 3, ks8 = (seg & 7) * 8;
      int kg = k0 + ks8;
      int b = mb * 64 + row;
      const unsigned short* src =
          (kg < 512) ? (hs + (size_t)b * HD + kg) : (hl + (size_t)b * HD + (kg - 512));
      *(short8*)(&As2[row][ks8]) = *(const short8*)src;
    }
#pragma unroll
    for (int i = 0; i < 4; ++i) {
      int seg = tid + i * 256;
      int n = seg >> 3, ks8 = (seg & 7) * 8;
      *(short8*)(&Bs2[n][ks8]) =
          *(const short8*)(WTo + (size_t)(nb * 128 + n) * 1024 + k0 + ks8);
    }
    __syncthreads();
#pragma unroll
    for (int ks = 0; ks < 64; ks += 32) {
      int kq = ks + quad * 8;
      bf16x8 a0 = __builtin_bit_cast(bf16x8, *(const short8*)(&As2[wm * 32 + lrow][kq]));
      bf16x8 a1 = __builtin_bit_cast(bf16x8, *(const short8*)(&As2[wm * 32 + 16 + lrow][kq]));
#pragma unroll
      for (int nt = 0; nt < 4; ++nt) {
        bf16x8 bfr = __builtin_bit_cast(bf16x8, *(const short8*)(&Bs2[wn * 64 + nt * 16 + lrow][kq]));
        acc[nt] = __builtin_amdgcn_mfma_f32_16x16x32_bf16(a0, bfr, acc[nt], 0, 0, 0);
        acc[4 + nt] = __builtin_amdgcn_mfma_f32_16x16x32_bf16(a1, bfr, acc[4 + nt], 0, 0, 0);
      }
    }
    __syncthreads();
  }
#pragma unroll
  for (int mt = 0; mt < 2; ++mt) {
#pragma unroll
    for (int nt = 0; nt < 4; ++nt) {
      int n = nb * 128 + wn * 64 + nt * 16 + lrow;
      float bv = ob[n];
#pragma unroll
      for (int r = 0; r < 4; ++r) {
        int b = mb * 64 + wm * 32 + mt * 16 + quad * 4 + r;
        out[(size_t)b * HD + n] = tanhf_(acc[mt * 4 + nt][r] + bv);
      }
    }
  }
}

extern "C" void kernel_launch(void* const* d_in, const int* in_sizes, int n_in,
                              void* d_out, int out_size, void* d_ws, size_t ws_size,
                              hipStream_t stream) {
  (void)in_sizes; (void)n_in; (void)out_size; (void)ws_size;
  const float* xs = (const float*)d_in[0];
  const float* xl = (const float*)d_in[1];
  const float* sW = (const float*)d_in[4];
  const float* sb = (const float*)d_in[5];
  const float* lW = (const float*)d_in[6];
  const float* lb = (const float*)d_in[7];
  const float* oW = (const float*)d_in[8];
  const float* ob = (const float*)d_in[9];

  char* w = (char*)d_ws;
  int* bar = (int*)w;                                   // 256 B barrier counters
  unsigned short* WTs = (unsigned short*)(w + 256);     // [2048][640]
  unsigned short* WTl = WTs + (size_t)G4 * KD;
  unsigned short* WTo = WTl + (size_t)G4 * KD;          // [512][1024]
  unsigned short* xTs = WTo + (size_t)HD * 1024;        // [128][512][128]
  unsigned short* xTl = xTs + (size_t)128 * 512 * 128;
  unsigned short* hs0 = xTl + (size_t)128 * 512 * 128;
  unsigned short* hs1 = hs0 + (size_t)512 * HD;
  unsigned short* hl0 = hs1 + (size_t)512 * HD;
  unsigned short* hl1 = hl0 + (size_t)512 * HD;

  hipMemsetAsync(bar, 0, 256, stream);
  transpose_f32_bf16<<<(640 / 64) * (2048 / 64), 256, 0, stream>>>(sW, WTs, 640, 2048);
  transpose_f32_bf16<<<(640 / 64) * (2048 / 64), 256, 0, stream>>>(lW, WTl, 640, 2048);
  transpose_f32_bf16<<<(1024 / 64) * (512 / 64), 256, 0, stream>>>(oW, WTo, 1024, 512);
  xconv<<<1024, 256, 0, stream>>>(xs, xl, xTs, xTl);

  const float* sbp = sb; const float* lbp = lb;
  const unsigned short *xTs_c = xTs, *xTl_c = xTl, *WTs_c = WTs, *WTl_c = WTl;
  unsigned short *a_hs0 = hs0, *a_hs1 = hs1, *a_hl0 = hl0, *a_hl1 = hl1;
  int* a_bar = bar;
  void* args[] = {(void*)&xTs_c, (void*)&xTl_c, (void*)&WTs_c, (void*)&WTl_c,
                  (void*)&sbp, (void*)&lbp, (void*)&a_hs0, (void*)&a_hs1,
                  (void*)&a_hl0, (void*)&a_hl1, (void*)&a_bar};
  hipError_t e = hipLaunchCooperativeKernel((const void*)lstm_persistent,
                                            dim3(256), dim3(256), args, 0, stream);
  if (e != hipSuccess) {
    // co-residency is structural (256 blocks, 1/CU); fall back to plain launch
    lstm_persistent<<<256, 256, 0, stream>>>(xTs, xTl, WTs, WTl, sb, lb,
                                             hs0, hs1, hl0, hl1, bar);
  }
  // t=127 wrote buf0
  out_gemm<<<32, 256, 0, stream>>>(hs0, hl0, WTo, ob, (float*)d_out);
}

// Round 4
// 2006.341 us; speedup vs baseline: 1.5320x; 1.5320x over previous
//
#include <hip/hip_runtime.h>

// Problem: B=512, T=128, I=128, H=512 (fp32 in/out; bf16 MFMA internally)
#define HD 512
#define KD 640
#define G4 2048

typedef short short8 __attribute__((ext_vector_type(8)));
typedef __bf16 bf16x8 __attribute__((ext_vector_type(8)));
typedef float floatx4 __attribute__((ext_vector_type(4)));

static __device__ __forceinline__ unsigned short f2bf(float f) {
  unsigned int u = __float_as_uint(f);
  u += 0x7fffu + ((u >> 16) & 1u);   // RNE
  return (unsigned short)(u >> 16);
}
static __device__ __forceinline__ float sigmoidf_(float x) {
  return 1.f / (1.f + __expf(-x));
}
static __device__ __forceinline__ float tanhf_(float x) {
  float ax = fabsf(x);
  float e = __expf(-2.f * ax);
  float r = 1.f - 2.f * e / (1.f + e);
  return copysignf(r, x);
}

// ---------------- transpose + cast: src[R][C] fp32 -> dst[C][R] bf16
__global__ __launch_bounds__(256) void transpose_f32_bf16(
    const float* __restrict__ src, unsigned short* __restrict__ dst,
    int R, int C) {
  __shared__ unsigned short tile[64][80];
  int nR = R >> 6;
  int tr = blockIdx.x % nR;
  int tc = blockIdx.x / nR;
  int tid = threadIdx.x;
#pragma unroll
  for (int i = 0; i < 2; ++i) {
    int seg = tid + i * 256;
    int row = seg >> 3, ks8 = (seg & 7) * 8;
    const float* p = src + (size_t)(tr * 64 + row) * C + tc * 64 + ks8;
    short8 v;
#pragma unroll
    for (int q = 0; q < 8; ++q) v[q] = (short)f2bf(p[q]);
    *(short8*)(&tile[row][ks8]) = v;
  }
  __syncthreads();
#pragma unroll
  for (int i = 0; i < 2; ++i) {
    int seg = tid + i * 256;
    int cl = seg >> 3, rs8 = (seg & 7) * 8;
    short8 v;
#pragma unroll
    for (int q = 0; q < 8; ++q) v[q] = (short)tile[rs8 + q][cl];
    *(short8*)(dst + (size_t)(tc * 64 + cl) * R + tr * 64 + rs8) = v;
  }
}

// ---------------- x convert: x[b][t][i] fp32 -> xT[t][b][i] bf16
__global__ __launch_bounds__(256) void xconv(
    const float* __restrict__ xs, const float* __restrict__ xl,
    unsigned short* __restrict__ xTs, unsigned short* __restrict__ xTl) {
  int t = blockIdx.x & 127;
  int bc = (blockIdx.x >> 7) & 3;
  int which = blockIdx.x >> 9;
  const float* x = which ? xl : xs;
  unsigned short* xT = which ? xTl : xTs;
  int b0 = bc * 128;
#pragma unroll
  for (int i = 0; i < 8; ++i) {
    int seg = threadIdx.x + i * 256;
    int bl_ = seg >> 4, i8 = (seg & 15) * 8;
    const float* p = x + (size_t)(b0 + bl_) * 16384 + t * 128 + i8;
    short8 v;
#pragma unroll
    for (int q = 0; q < 8; ++q) v[q] = (short)f2bf(p[q]);
    *(short8*)(xT + ((size_t)t * 512 + b0 + bl_) * 128 + i8) = v;
  }
}

// ---------------- persistent dual-LSTM over all 128 steps
// grid 256 = lstm(2) x mb(16: 32 rows) x nb(8: 64 h, all 4 gates)
// block = 4 waves; wave w computes gate w for all 64 h, 32 rows.
// B-weights (640x64x4g per block) live entirely in VGPRs (320/lane).
// Sync: per-block monotonic flag STORES (no RMW), h via agent-scope (sc1)
// stores to LLC, acquire = inv-only fence (nothing dirty in L2).
__global__ __launch_bounds__(256, 1) void lstm_persistent(
    const unsigned short* __restrict__ xTs, const unsigned short* __restrict__ xTl,
    const unsigned short* __restrict__ WTs, const unsigned short* __restrict__ WTl,
    const float* __restrict__ bs, const float* __restrict__ bl,
    unsigned short* __restrict__ hs0, unsigned short* __restrict__ hs1,
    unsigned short* __restrict__ hl0, unsigned short* __restrict__ hl1,
    int* __restrict__ flags) {
  const int bid = blockIdx.x;
  const int lstm = bid & 1;
  const int mb = (bid >> 1) & 15;
  const int nb = bid >> 5;
  const int grp = lstm * 16 + mb;          // 32 groups x 8 blocks
  const int b0 = mb * 32;
  const int H0 = nb * 64;

  const unsigned short* xT = lstm ? xTl : xTs;
  const unsigned short* WT = lstm ? WTl : WTs;
  const float* bias = lstm ? bl : bs;
  unsigned short* h0 = lstm ? hl0 : hs0;
  unsigned short* h1 = lstm ? hl1 : hs1;

  // LDS: As [32][648]us = 41472 B ; g_lds [4][32][64]f32 = 32768 B (ALIASES As)
  //      c_lds [32][64]f32 @41472 ; bias_lds [4][64]f32 @49664 ; total 50688 B
  __shared__ unsigned long long smem_[50688 / 8];
  unsigned short* As = (unsigned short*)smem_;
  float* g_lds = (float*)smem_;
  float* c_lds = (float*)((char*)smem_ + 41472);
  float* bias_lds = (float*)((char*)smem_ + 49664);

  const int tid = threadIdx.x;
  const int wave = tid >> 6;   // = gate index
  const int lane = tid & 63;
  const int quad = lane >> 4;
  const int lrow = lane & 15;

  bias_lds[tid] = bias[(tid >> 6) * HD + H0 + (tid & 63)];

  // B fragments in registers: breg[nt][kc] covers cols H0+nt*16..+16 of gate
  // `wave`, k = kc*32 + quad*8 .. +8
  bf16x8 breg[4][20];
#pragma unroll
  for (int nt = 0; nt < 4; ++nt) {
    int wrow = wave * HD + H0 + nt * 16 + lrow;
    const unsigned short* wp = WT + (size_t)wrow * KD + quad * 8;
#pragma unroll
    for (int kc = 0; kc < 20; ++kc)
      breg[nt][kc] = __builtin_bit_cast(bf16x8, *(const short8*)(wp + kc * 32));
  }

#pragma unroll 1
  for (int t = 0; t < 128; ++t) {
    const unsigned short* hr = (t & 1) ? h1 : h0;
    unsigned short* hw = (t & 1) ? h0 : h1;

    // ---- wait for h(t) from the other 7 blocks of this group
    if (t > 0) {
      if (wave == 0) {
        const int tgt = t;
        while (true) {
          int v = __hip_atomic_load(flags + grp * 16 + (lane & 7),
                                    __ATOMIC_RELAXED, __HIP_MEMORY_SCOPE_AGENT);
          if (__ballot(v >= tgt) == 0xFFFFFFFFFFFFFFFFull) break;
          __builtin_amdgcn_s_sleep(1);
        }
      }
      __syncthreads();
      __builtin_amdgcn_fence(__ATOMIC_ACQUIRE, "agent");  // inv stale L2 h lines
    }

    // ---- stage A = [x_t | h_t] (32 rows x 640 k) into LDS, one burst
#pragma unroll
    for (int i = 0; i < 2; ++i) {       // x: 32 rows x 128
      int seg = tid + i * 256;
      int row = seg >> 4, ch = seg & 15;
      short8 v = *(const short8*)(xT + ((size_t)t * 512 + b0 + row) * 128 + ch * 8);
      *(short8*)(As + (size_t)row * 648 + ch * 8) = v;
    }
#pragma unroll
    for (int i = 0; i < 8; ++i) {       // h: 32 rows x 512
      int seg = tid + i * 256;
      int row = seg >> 6, ch = seg & 63;
      short8 v;
      if (t > 0) v = *(const short8*)(hr + (size_t)(b0 + row) * HD + ch * 8);
      else       v = (short8){0, 0, 0, 0, 0, 0, 0, 0};
      *(short8*)(As + (size_t)row * 648 + 128 + ch * 8) = v;
    }
    __syncthreads();

    // ---- GEMM: 160 MFMA off LDS A-frags x register B-frags
    floatx4 acc[2][4];
#pragma unroll
    for (int mt = 0; mt < 2; ++mt)
#pragma unroll
      for (int nt = 0; nt < 4; ++nt) acc[mt][nt] = (floatx4){0.f, 0.f, 0.f, 0.f};
#pragma unroll
    for (int kc = 0; kc < 20; ++kc) {
      bf16x8 a0 = __builtin_bit_cast(bf16x8,
          *(const short8*)(As + (size_t)lrow * 648 + kc * 32 + quad * 8));
      bf16x8 a1 = __builtin_bit_cast(bf16x8,
          *(const short8*)(As + (size_t)(16 + lrow) * 648 + kc * 32 + quad * 8));
#pragma unroll
      for (int nt = 0; nt < 4; ++nt) {
        acc[0][nt] = __builtin_amdgcn_mfma_f32_16x16x32_bf16(a0, breg[nt][kc], acc[0][nt], 0, 0, 0);
        acc[1][nt] = __builtin_amdgcn_mfma_f32_16x16x32_bf16(a1, breg[nt][kc], acc[1][nt], 0, 0, 0);
      }
    }

    __syncthreads();  // As reads done before g_lds (alias) writes
#pragma unroll
    for (int mt = 0; mt < 2; ++mt)
#pragma unroll
      for (int nt = 0; nt < 4; ++nt)
#pragma unroll
        for (int r = 0; r < 4; ++r)
          g_lds[wave * 2048 + (mt * 16 + quad * 4 + r) * 64 + nt * 16 + lrow] =
              acc[mt][nt][r];
    __syncthreads();

    // ---- gate math: thread -> b = tid>>3 (32 rows), 8 h at h8=(tid&7)*8
    {
      int b = tid >> 3, h8 = (tid & 7) * 8;
      unsigned int hv[4];
      float cn8[8];
#pragma unroll
      for (int j = 0; j < 8; ++j) {
        int hl_ = h8 + j;
        float fg = g_lds[0 * 2048 + b * 64 + hl_] + bias_lds[0 * 64 + hl_];
        float ig = g_lds[1 * 2048 + b * 64 + hl_] + bias_lds[1 * 64 + hl_];
        float og = g_lds[2 * 2048 + b * 64 + hl_] + bias_lds[2 * 64 + hl_];
        float cg = g_lds[3 * 2048 + b * 64 + hl_] + bias_lds[3 * 64 + hl_];
        float cold = (t > 0) ? c_lds[b * 64 + hl_] : 0.f;
        float cn = sigmoidf_(fg) * cold + sigmoidf_(ig) * tanhf_(cg);
        float hn = sigmoidf_(og) * tanhf_(cn);
        cn8[j] = cn;
        unsigned int hb = f2bf(hn);
        if (j & 1) hv[j >> 1] |= hb << 16;
        else       hv[j >> 1] = hb;
      }
#pragma unroll
      for (int j = 0; j < 8; ++j) c_lds[b * 64 + h8 + j] = cn8[j];
      // h out: agent-scope (sc1) stores -> LLC, dirty nothing in L2
      unsigned int* hw32 = (unsigned int*)hw;
      size_t base = ((size_t)(b0 + b) * HD + H0 + h8) >> 1;
#pragma unroll
      for (int d = 0; d < 4; ++d)
        __hip_atomic_store(hw32 + base + d, hv[d],
                           __ATOMIC_RELAXED, __HIP_MEMORY_SCOPE_AGENT);
    }
    __syncthreads();  // drains every thread's vmcnt (h stores at LLC) + g_lds reads done

    if (tid == 0 && t < 127)
      __hip_atomic_store(flags + grp * 16 + nb, t + 1,
                         __ATOMIC_RELAXED, __HIP_MEMORY_SCOPE_AGENT);
  }
}

// ---------------- out = tanh(concat(hs,hl) @ out_W + out_b), fp32 out
__global__ __launch_bounds__(256) void out_gemm(
    const unsigned short* __restrict__ hs, const unsigned short* __restrict__ hl,
    const unsigned short* __restrict__ WTo,  // [512][1024] bf16
    const float* __restrict__ ob, float* __restrict__ out) {
  const int bx = blockIdx.x;
  const int mb = bx & 7;
  const int nb = bx >> 3;

  __shared__ unsigned short As2[64][88];
  __shared__ unsigned short Bs2[128][88];

  const int tid = threadIdx.x;
  const int wave = tid >> 6;
  const int lane = tid & 63;
  const int quad = lane >> 4;
  const int lrow = lane & 15;
  const int wm = wave & 1;
  const int wn = wave >> 1;

  floatx4 acc[8];
#pragma unroll
  for (int i = 0; i < 8; ++i) acc[i] = (floatx4){0.f, 0.f, 0.f, 0.f};

  for (int k0 = 0; k0 < 1024; k0 += 64) {
#pragma unroll
    for (int i = 0; i < 2; ++i) {
      int seg = tid + i * 256;
      int row = seg >> 3, ks8 = (seg & 7) * 8;
      int kg = k0 + ks8;
      int b = mb * 64 + row;
      const unsigned short* src =
          (kg < 512) ? (hs + (size_t)b * HD + kg) : (hl + (size_t)b * HD + (kg - 512));
      *(short8*)(&As2[row][ks8]) = *(const short8*)src;
    }
#pragma unroll
    for (int i = 0; i < 4; ++i) {
      int seg = tid + i * 256;
      int n = seg >> 3, ks8 = (seg & 7) * 8;
      *(short8*)(&Bs2[n][ks8]) =
          *(const short8*)(WTo + (size_t)(nb * 128 + n) * 1024 + k0 + ks8);
    }
    __syncthreads();
#pragma unroll
    for (int ks = 0; ks < 64; ks += 32) {
      int kq = ks + quad * 8;
      bf16x8 a0 = __builtin_bit_cast(bf16x8, *(const short8*)(&As2[wm * 32 + lrow][kq]));
      bf16x8 a1 = __builtin_bit_cast(bf16x8, *(const short8*)(&As2[wm * 32 + 16 + lrow][kq]));
#pragma unroll
      for (int nt = 0; nt < 4; ++nt) {
        bf16x8 bfr = __builtin_bit_cast(bf16x8, *(const short8*)(&Bs2[wn * 64 + nt * 16 + lrow][kq]));
        acc[nt] = __builtin_amdgcn_mfma_f32_16x16x32_bf16(a0, bfr, acc[nt], 0, 0, 0);
        acc[4 + nt] = __builtin_amdgcn_mfma_f32_16x16x32_bf16(a1, bfr, acc[4 + nt], 0, 0, 0);
      }
    }
    __syncthreads();
  }
#pragma unroll
  for (int mt = 0; mt < 2; ++mt) {
#pragma unroll
    for (int nt = 0; nt < 4; ++nt) {
      int n = nb * 128 + wn * 64 + nt * 16 + lrow;
      float bv = ob[n];
#pragma unroll
      for (int r = 0; r < 4; ++r) {
        int b = mb * 64 + wm * 32 + mt * 16 + quad * 4 + r;
        out[(size_t)b * HD + n] = tanhf_(acc[mt * 4 + nt][r] + bv);
      }
    }
  }
}

extern "C" void kernel_launch(void* const* d_in, const int* in_sizes, int n_in,
                              void* d_out, int out_size, void* d_ws, size_t ws_size,
                              hipStream_t stream) {
  (void)in_sizes; (void)n_in; (void)out_size; (void)ws_size;
  const float* xs = (const float*)d_in[0];
  const float* xl = (const float*)d_in[1];
  const float* sW = (const float*)d_in[4];
  const float* sb = (const float*)d_in[5];
  const float* lW = (const float*)d_in[6];
  const float* lb = (const float*)d_in[7];
  const float* oW = (const float*)d_in[8];
  const float* ob = (const float*)d_in[9];

  char* w = (char*)d_ws;
  int* flags = (int*)w;                                 // 32 grp x 16 ints (64B lines)
  unsigned short* WTs = (unsigned short*)(w + 4096);    // [2048][640]
  unsigned short* WTl = WTs + (size_t)G4 * KD;
  unsigned short* WTo = WTl + (size_t)G4 * KD;          // [512][1024]
  unsigned short* xTs = WTo + (size_t)HD * 1024;        // [128][512][128]
  unsigned short* xTl = xTs + (size_t)128 * 512 * 128;
  unsigned short* hs0 = xTl + (size_t)128 * 512 * 128;
  unsigned short* hs1 = hs0 + (size_t)512 * HD;
  unsigned short* hl0 = hs1 + (size_t)512 * HD;
  unsigned short* hl1 = hl0 + (size_t)512 * HD;

  hipMemsetAsync(flags, 0, 4096, stream);
  transpose_f32_bf16<<<(640 / 64) * (2048 / 64), 256, 0, stream>>>(sW, WTs, 640, 2048);
  transpose_f32_bf16<<<(640 / 64) * (2048 / 64), 256, 0, stream>>>(lW, WTl, 640, 2048);
  transpose_f32_bf16<<<(1024 / 64) * (512 / 64), 256, 0, stream>>>(oW, WTo, 1024, 512);
  xconv<<<1024, 256, 0, stream>>>(xs, xl, xTs, xTl);

  const float* sbp = sb; const float* lbp = lb;
  const unsigned short *xTs_c = xTs, *xTl_c = xTl, *WTs_c = WTs, *WTl_c = WTl;
  unsigned short *a_hs0 = hs0, *a_hs1 = hs1, *a_hl0 = hl0, *a_hl1 = hl1;
  int* a_flags = flags;
  void* args[] = {(void*)&xTs_c, (void*)&xTl_c, (void*)&WTs_c, (void*)&WTl_c,
                  (void*)&sbp, (void*)&lbp, (void*)&a_hs0, (void*)&a_hs1,
                  (void*)&a_hl0, (void*)&a_hl1, (void*)&a_flags};
  hipError_t e = hipLaunchCooperativeKernel((const void*)lstm_persistent,
                                            dim3(256), dim3(256), args, 0, stream);
  if (e != hipSuccess) {
    lstm_persistent<<<256, 256, 0, stream>>>(xTs, xTl, WTs, WTl, sb, lb,
                                             hs0, hs1, hl0, hl1, flags);
  }
  // h(128) landed in buf0
  out_gemm<<<32, 256, 0, stream>>>(hs0, hl0, WTo, ob, (float*)d_out);
}

// Round 5
// 915.043 us; speedup vs baseline: 3.3592x; 2.1926x over previous
//
#include <hip/hip_runtime.h>

// Problem: B=512, T=128, I=128, H=512 (fp32 in/out; bf16 MFMA internally)
#define HD 512
#define KD 640
#define G4 2048

typedef short short8 __attribute__((ext_vector_type(8)));
typedef __bf16 bf16x8 __attribute__((ext_vector_type(8)));
typedef float floatx4 __attribute__((ext_vector_type(4)));
typedef unsigned int uintx4 __attribute__((ext_vector_type(4)));

static __device__ __forceinline__ unsigned short f2bf(float f) {
  unsigned int u = __float_as_uint(f);
  u += 0x7fffu + ((u >> 16) & 1u);   // RNE
  return (unsigned short)(u >> 16);
}
static __device__ __forceinline__ float sigmoidf_(float x) {
  return 1.f / (1.f + __expf(-x));
}
static __device__ __forceinline__ float tanhf_(float x) {
  float ax = fabsf(x);
  float e = __expf(-2.f * ax);
  float r = 1.f - 2.f * e / (1.f + e);
  return copysignf(r, x);
}
// agent-coherent 16B ops: sc0 sc1 = bypass L1/L2, meet at MALL (no buffer_inv needed)
static __device__ __forceinline__ uintx4 load16_cc(unsigned long long a) {
  uintx4 r;
  asm volatile("global_load_dwordx4 %0, %1, off sc0 sc1" : "=v"(r) : "v"(a) : "memory");
  return r;
}
static __device__ __forceinline__ void store16_cc(unsigned long long a, uintx4 v) {
  asm volatile("global_store_dwordx4 %0, %1, off sc0 sc1" :: "v"(a), "v"(v) : "memory");
}
static __device__ __forceinline__ void waitcnt_vm0() {
  asm volatile("s_waitcnt vmcnt(0)" ::: "memory");
}

// ---------------- transpose + cast: src[R][C] fp32 -> dst[C][R] bf16
__global__ __launch_bounds__(256) void transpose_f32_bf16(
    const float* __restrict__ src, unsigned short* __restrict__ dst,
    int R, int C) {
  __shared__ unsigned short tile[64][80];
  int nR = R >> 6;
  int tr = blockIdx.x % nR;
  int tc = blockIdx.x / nR;
  int tid = threadIdx.x;
#pragma unroll
  for (int i = 0; i < 2; ++i) {
    int seg = tid + i * 256;
    int row = seg >> 3, ks8 = (seg & 7) * 8;
    const float* p = src + (size_t)(tr * 64 + row) * C + tc * 64 + ks8;
    short8 v;
#pragma unroll
    for (int q = 0; q < 8; ++q) v[q] = (short)f2bf(p[q]);
    *(short8*)(&tile[row][ks8]) = v;
  }
  __syncthreads();
#pragma unroll
  for (int i = 0; i < 2; ++i) {
    int seg = tid + i * 256;
    int cl = seg >> 3, rs8 = (seg & 7) * 8;
    short8 v;
#pragma unroll
    for (int q = 0; q < 8; ++q) v[q] = (short)tile[rs8 + q][cl];
    *(short8*)(dst + (size_t)(tc * 64 + cl) * R + tr * 64 + rs8) = v;
  }
}

// ---------------- x convert: x[b][t][i] fp32 -> xT[t][b][i] bf16
__global__ __launch_bounds__(256) void xconv(
    const float* __restrict__ xs, const float* __restrict__ xl,
    unsigned short* __restrict__ xTs, unsigned short* __restrict__ xTl) {
  int t = blockIdx.x & 127;
  int bc = (blockIdx.x >> 7) & 3;
  int which = blockIdx.x >> 9;
  const float* x = which ? xl : xs;
  unsigned short* xT = which ? xTl : xTs;
  int b0 = bc * 128;
#pragma unroll
  for (int i = 0; i < 8; ++i) {
    int seg = threadIdx.x + i * 256;
    int bl_ = seg >> 4, i8 = (seg & 15) * 8;
    const float* p = x + (size_t)(b0 + bl_) * 16384 + t * 128 + i8;
    short8 v;
#pragma unroll
    for (int q = 0; q < 8; ++q) v[q] = (short)f2bf(p[q]);
    *(short8*)(xT + ((size_t)t * 512 + b0 + bl_) * 128 + i8) = v;
  }
}

// ---------------- persistent dual-LSTM over all 128 steps
// grid 256 = lstm(2) x mb(16: 32 rows) x nb(8: 64 h, all 4 gates)
// wave w = gate w. B-weights in registers. c + bias in registers.
// h exchange: 16B sc0sc1 write-through stores / L2-bypass loads (meet at MALL);
// per-block monotonic flag stores, no RMW, no buffer_inv.
__global__ __launch_bounds__(256, 1) void lstm_persistent(
    const unsigned short* __restrict__ xTs, const unsigned short* __restrict__ xTl,
    const unsigned short* __restrict__ WTs, const unsigned short* __restrict__ WTl,
    const float* __restrict__ bs, const float* __restrict__ bl,
    unsigned short* __restrict__ hs0, unsigned short* __restrict__ hs1,
    unsigned short* __restrict__ hl0, unsigned short* __restrict__ hl1,
    int* __restrict__ flags) {
  const int bid = blockIdx.x;
  const int lstm = bid & 1;
  const int mb = (bid >> 1) & 15;
  const int nb = bid >> 5;
  const int grp = lstm * 16 + mb;          // 32 groups x 8 blocks
  const int b0 = mb * 32;
  const int H0 = nb * 64;

  const unsigned short* xT = lstm ? xTl : xTs;
  const unsigned short* WT = lstm ? WTl : WTs;
  const float* bias = lstm ? bl : bs;
  unsigned short* h0 = lstm ? hl0 : hs0;
  unsigned short* h1 = lstm ? hl1 : hs1;

  // LDS: As [32 rows][648 us] = 41472 B ; g_lds [4][32][68]f32 = 34816 B (aliases As)
  __shared__ unsigned long long smem_[41472 / 8];
  unsigned short* As = (unsigned short*)smem_;
  float* g_lds = (float*)smem_;

  const int tid = threadIdx.x;
  const int wave = tid >> 6;   // = gate index
  const int lane = tid & 63;
  const int quad = lane >> 4;
  const int lrow = lane & 15;

  // epilogue assignment (fixed across t): row ep_b, 8 h at ep_h8
  const int ep_b = tid >> 3;
  const int ep_h8 = (tid & 7) * 8;

  // bias + c state in registers
  floatx4 bias_r[4][2];
#pragma unroll
  for (int g = 0; g < 4; ++g) {
    bias_r[g][0] = *(const floatx4*)(bias + g * HD + H0 + ep_h8);
    bias_r[g][1] = *(const floatx4*)(bias + g * HD + H0 + ep_h8 + 4);
  }
  float c_r[8];
#pragma unroll
  for (int j = 0; j < 8; ++j) c_r[j] = 0.f;

  // B fragments in registers: breg[nt][kc]
  bf16x8 breg[4][20];
#pragma unroll
  for (int nt = 0; nt < 4; ++nt) {
    int wrow = wave * HD + H0 + nt * 16 + lrow;
    const unsigned short* wp = WT + (size_t)wrow * KD + quad * 8;
#pragma unroll
    for (int kc = 0; kc < 20; ++kc)
      breg[nt][kc] = __builtin_bit_cast(bf16x8, *(const short8*)(wp + kc * 32));
  }

  const unsigned long long hst0 =
      (unsigned long long)(h1 + (size_t)(b0 + ep_b) * HD + H0 + ep_h8);  // t even writes h1
  const unsigned long long hst1 =
      (unsigned long long)(h0 + (size_t)(b0 + ep_b) * HD + H0 + ep_h8);  // t odd  writes h0

#pragma unroll 1
  for (int t = 0; t < 128; ++t) {
    const unsigned short* hr = (t & 1) ? h1 : h0;

    // ---- stage x_t (h-independent) into As cols [0,128)
#pragma unroll
    for (int i = 0; i < 2; ++i) {
      int seg = tid + i * 256;
      int row = seg >> 4, ch = seg & 15;
      short8 v = *(const short8*)(xT + ((size_t)t * 512 + b0 + row) * 128 + ch * 8);
      *(short8*)((char*)As + (size_t)row * 1296 + ch * 16) = v;
    }

    // ---- wait for h(t) flags from this group's 8 blocks
    if (t > 0) {
      if (wave == 0) {
        while (true) {
          int v = __hip_atomic_load(flags + grp * 16 + (lane & 7),
                                    __ATOMIC_RELAXED, __HIP_MEMORY_SCOPE_AGENT);
          if (__ballot(v >= t) == 0xFFFFFFFFFFFFFFFFull) break;
          __builtin_amdgcn_s_sleep(1);
        }
      }
      __syncthreads();
      // h: 32 rows x 512, L2-bypass loads -> LDS cols [128,640)
      uintx4 hv_[8];
#pragma unroll
      for (int i = 0; i < 8; ++i) {
        int chunk = tid + i * 256;
        int row = chunk >> 6, ch = chunk & 63;
        hv_[i] = load16_cc((unsigned long long)(hr + (size_t)(b0 + row) * HD + ch * 8));
      }
      waitcnt_vm0();
#pragma unroll
      for (int i = 0; i < 8; ++i) {
        int chunk = tid + i * 256;
        int row = chunk >> 6, ch = chunk & 63;
        *(uintx4*)((char*)As + (size_t)row * 1296 + 256 + ch * 16) = hv_[i];
      }
    } else {
#pragma unroll
      for (int i = 0; i < 8; ++i) {
        int chunk = tid + i * 256;
        int row = chunk >> 6, ch = chunk & 63;
        *(uintx4*)((char*)As + (size_t)row * 1296 + 256 + ch * 16) = (uintx4){0, 0, 0, 0};
      }
    }
    __syncthreads();

    // ---- GEMM: 160 MFMA/wave off LDS A-frags x register B-frags
    floatx4 acc[2][4];
#pragma unroll
    for (int mt = 0; mt < 2; ++mt)
#pragma unroll
      for (int nt = 0; nt < 4; ++nt) acc[mt][nt] = (floatx4){0.f, 0.f, 0.f, 0.f};
#pragma unroll
    for (int kc = 0; kc < 20; ++kc) {
      bf16x8 a0 = __builtin_bit_cast(bf16x8,
          *(const short8*)((char*)As + (size_t)lrow * 1296 + kc * 64 + quad * 16));
      bf16x8 a1 = __builtin_bit_cast(bf16x8,
          *(const short8*)((char*)As + (size_t)(16 + lrow) * 1296 + kc * 64 + quad * 16));
#pragma unroll
      for (int nt = 0; nt < 4; ++nt) {
        acc[0][nt] = __builtin_amdgcn_mfma_f32_16x16x32_bf16(a0, breg[nt][kc], acc[0][nt], 0, 0, 0);
        acc[1][nt] = __builtin_amdgcn_mfma_f32_16x16x32_bf16(a1, breg[nt][kc], acc[1][nt], 0, 0, 0);
      }
    }

    __syncthreads();  // As reads done before g_lds (alias) writes
    // scatter pre-activations: g_lds[gate][row(32)][68] (padded rows)
#pragma unroll
    for (int mt = 0; mt < 2; ++mt)
#pragma unroll
      for (int nt = 0; nt < 4; ++nt)
#pragma unroll
        for (int r = 0; r < 4; ++r)
          g_lds[(wave * 32 + mt * 16 + quad * 4 + r) * 68 + nt * 16 + lrow] =
              acc[mt][nt][r];
    __syncthreads();

    // ---- gate math (registers; g via padded-LDS float4 reads)
    {
      floatx4 gv[4][2];
#pragma unroll
      for (int g = 0; g < 4; ++g) {
        gv[g][0] = *(const floatx4*)(g_lds + (g * 32 + ep_b) * 68 + ep_h8);
        gv[g][1] = *(const floatx4*)(g_lds + (g * 32 + ep_b) * 68 + ep_h8 + 4);
      }
      uintx4 hv;
#pragma unroll
      for (int j = 0; j < 8; ++j) {
        int w = j >> 2, l = j & 3;
        float fg = gv[0][w][l] + bias_r[0][w][l];
        float ig = gv[1][w][l] + bias_r[1][w][l];
        float og = gv[2][w][l] + bias_r[2][w][l];
        float cg = gv[3][w][l] + bias_r[3][w][l];
        float cn = sigmoidf_(fg) * c_r[j] + sigmoidf_(ig) * tanhf_(cg);
        float hn = sigmoidf_(og) * tanhf_(cn);
        c_r[j] = cn;
        unsigned int hb = f2bf(hn);
        if (j & 1) hv[j >> 1] |= hb << 16;
        else       hv[j >> 1] = hb;
      }
      store16_cc((t & 1) ? hst1 : hst0, hv);   // write-through to MALL
      waitcnt_vm0();                           // store globally visible
    }
    __syncthreads();  // whole block's h out + g_lds reads done

    if (tid == 0 && t < 127)
      __hip_atomic_store(flags + grp * 16 + nb, t + 1,
                         __ATOMIC_RELAXED, __HIP_MEMORY_SCOPE_AGENT);
  }
}

// ---------------- out = tanh(concat(hs,hl) @ out_W + out_b), fp32 out
__global__ __launch_bounds__(256) void out_gemm(
    const unsigned short* __restrict__ hs, const unsigned short* __restrict__ hl,
    const unsigned short* __restrict__ WTo,  // [512][1024] bf16
    const float* __restrict__ ob, float* __restrict__ out) {
  const int bx = blockIdx.x;
  const int mb = bx & 7;
  const int nb = bx >> 3;

  __shared__ unsigned short As2[64][88];
  __shared__ unsigned short Bs2[128][88];

  const int tid = threadIdx.x;
  const int wave = tid >> 6;
  const int lane = tid & 63;
  const int quad = lane >> 4;
  const int lrow = lane & 15;
  const int wm = wave & 1;
  const int wn = wave >> 1;

  floatx4 acc[8];
#pragma unroll
  for (int i = 0; i < 8; ++i) acc[i] = (floatx4){0.f, 0.f, 0.f, 0.f};

  for (int k0 = 0; k0 < 1024; k0 += 64) {
#pragma unroll
    for (int i = 0; i < 2; ++i) {
      int seg = tid + i * 256;
      int row = seg >> 3, ks8 = (seg & 7) * 8;
      int kg = k0 + ks8;
      int b = mb * 64 + row;
      const unsigned short* src =
          (kg < 512) ? (hs + (size_t)b * HD + kg) : (hl + (size_t)b * HD + (kg - 512));
      *(short8*)(&As2[row][ks8]) = *(const short8*)src;
    }
#pragma unroll
    for (int i = 0; i < 4; ++i) {
      int seg = tid + i * 256;
      int n = seg >> 3, ks8 = (seg & 7) * 8;
      *(short8*)(&Bs2[n][ks8]) =
          *(const short8*)(WTo + (size_t)(nb * 128 + n) * 1024 + k0 + ks8);
    }
    __syncthreads();
#pragma unroll
    for (int ks = 0; ks < 64; ks += 32) {
      int kq = ks + quad * 8;
      bf16x8 a0 = __builtin_bit_cast(bf16x8, *(const short8*)(&As2[wm * 32 + lrow][kq]));
      bf16x8 a1 = __builtin_bit_cast(bf16x8, *(const short8*)(&As2[wm * 32 + 16 + lrow][kq]));
#pragma unroll
      for (int nt = 0; nt < 4; ++nt) {
        bf16x8 bfr = __builtin_bit_cast(bf16x8, *(const short8*)(&Bs2[wn * 64 + nt * 16 + lrow][kq]));
        acc[nt] = __builtin_amdgcn_mfma_f32_16x16x32_bf16(a0, bfr, acc[nt], 0, 0, 0);
        acc[4 + nt] = __builtin_amdgcn_mfma_f32_16x16x32_bf16(a1, bfr, acc[4 + nt], 0, 0, 0);
      }
    }
    __syncthreads();
  }
#pragma unroll
  for (int mt = 0; mt < 2; ++mt) {
#pragma unroll
    for (int nt = 0; nt < 4; ++nt) {
      int n = nb * 128 + wn * 64 + nt * 16 + lrow;
      float bv = ob[n];
#pragma unroll
      for (int r = 0; r < 4; ++r) {
        int b = mb * 64 + wm * 32 + mt * 16 + quad * 4 + r;
        out[(size_t)b * HD + n] = tanhf_(acc[mt * 4 + nt][r] + bv);
      }
    }
  }
}

extern "C" void kernel_launch(void* const* d_in, const int* in_sizes, int n_in,
                              void* d_out, int out_size, void* d_ws, size_t ws_size,
                              hipStream_t stream) {
  (void)in_sizes; (void)n_in; (void)out_size; (void)ws_size;
  const float* xs = (const float*)d_in[0];
  const float* xl = (const float*)d_in[1];
  const float* sW = (const float*)d_in[4];
  const float* sb = (const float*)d_in[5];
  const float* lW = (const float*)d_in[6];
  const float* lb = (const float*)d_in[7];
  const float* oW = (const float*)d_in[8];
  const float* ob = (const float*)d_in[9];

  char* w = (char*)d_ws;
  int* flags = (int*)w;                                 // 32 grp x 16 ints
  unsigned short* WTs = (unsigned short*)(w + 4096);    // [2048][640]
  unsigned short* WTl = WTs + (size_t)G4 * KD;
  unsigned short* WTo = WTl + (size_t)G4 * KD;          // [512][1024]
  unsigned short* xTs = WTo + (size_t)HD * 1024;        // [128][512][128]
  unsigned short* xTl = xTs + (size_t)128 * 512 * 128;
  unsigned short* hs0 = xTl + (size_t)128 * 512 * 128;
  unsigned short* hs1 = hs0 + (size_t)512 * HD;
  unsigned short* hl0 = hs1 + (size_t)512 * HD;
  unsigned short* hl1 = hl0 + (size_t)512 * HD;

  hipMemsetAsync(flags, 0, 4096, stream);
  transpose_f32_bf16<<<(640 / 64) * (2048 / 64), 256, 0, stream>>>(sW, WTs, 640, 2048);
  transpose_f32_bf16<<<(640 / 64) * (2048 / 64), 256, 0, stream>>>(lW, WTl, 640, 2048);
  transpose_f32_bf16<<<(1024 / 64) * (512 / 64), 256, 0, stream>>>(oW, WTo, 1024, 512);
  xconv<<<1024, 256, 0, stream>>>(xs, xl, xTs, xTl);

  const float* sbp = sb; const float* lbp = lb;
  const unsigned short *xTs_c = xTs, *xTl_c = xTl, *WTs_c = WTs, *WTl_c = WTl;
  unsigned short *a_hs0 = hs0, *a_hs1 = hs1, *a_hl0 = hl0, *a_hl1 = hl1;
  int* a_flags = flags;
  void* args[] = {(void*)&xTs_c, (void*)&xTl_c, (void*)&WTs_c, (void*)&WTl_c,
                  (void*)&sbp, (void*)&lbp, (void*)&a_hs0, (void*)&a_hs1,
                  (void*)&a_hl0, (void*)&a_hl1, (void*)&a_flags};
  hipError_t e = hipLaunchCooperativeKernel((const void*)lstm_persistent,
                                            dim3(256), dim3(256), args, 0, stream);
  if (e != hipSuccess) {
    lstm_persistent<<<256, 256, 0, stream>>>(xTs, xTl, WTs, WTl, sb, lb,
                                             hs0, hs1, hl0, hl1, flags);
  }
  // t=127 (odd) wrote h0 buffers
  out_gemm<<<32, 256, 0, stream>>>(hs0, hl0, WTo, ob, (float*)d_out);
}

// Round 7
// 858.674 us; speedup vs baseline: 3.5797x; 1.0656x over previous
//
#include <hip/hip_runtime.h>

// Problem: B=512, T=128, I=128, H=512 (fp32 in/out; bf16 MFMA internally)
#define HD 512
#define KD 640
#define G4 2048

typedef short short8 __attribute__((ext_vector_type(8)));
typedef __bf16 bf16x8 __attribute__((ext_vector_type(8)));
typedef float floatx4 __attribute__((ext_vector_type(4)));
typedef unsigned int uintx4 __attribute__((ext_vector_type(4)));

static __device__ __forceinline__ unsigned short f2bf(float f) {
  unsigned int u = __float_as_uint(f);
  u += 0x7fffu + ((u >> 16) & 1u);   // RNE
  return (unsigned short)(u >> 16);
}
static __device__ __forceinline__ float rcp_(float x) {
  return __builtin_amdgcn_rcpf(x);   // v_rcp_f32, ~1 ulp
}
static __device__ __forceinline__ float sigmoidf_(float x) {
  return rcp_(1.f + __expf(-x));
}
static __device__ __forceinline__ float tanhf_(float x) {
  float ax = fabsf(x);
  float e = __expf(-2.f * ax);
  float r = fmaf(-2.f * e, rcp_(1.f + e), 1.f);   // (1-e)/(1+e)
  return copysignf(r, x);
}
// agent-coherent 16B ops: sc0 sc1 = bypass L1/L2, meet at MALL
static __device__ __forceinline__ uintx4 load16_cc(unsigned long long a) {
  uintx4 r;
  asm volatile("global_load_dwordx4 %0, %1, off sc0 sc1" : "=v"(r) : "v"(a) : "memory");
  return r;
}
static __device__ __forceinline__ void store16_cc(unsigned long long a, uintx4 v) {
  asm volatile("global_store_dwordx4 %0, %1, off sc0 sc1" :: "v"(a), "v"(v) : "memory");
}
static __device__ __forceinline__ void waitcnt_vm0() {
  asm volatile("s_waitcnt vmcnt(0)" ::: "memory");
}

// ---------------- transpose + cast: src[R][C] fp32 -> dst[C][R] bf16
__global__ __launch_bounds__(256) void transpose_f32_bf16(
    const float* __restrict__ src, unsigned short* __restrict__ dst,
    int R, int C) {
  __shared__ unsigned short tile[64][80];
  int nR = R >> 6;
  int tr = blockIdx.x % nR;
  int tc = blockIdx.x / nR;
  int tid = threadIdx.x;
#pragma unroll
  for (int i = 0; i < 2; ++i) {
    int seg = tid + i * 256;
    int row = seg >> 3, ks8 = (seg & 7) * 8;
    const float* p = src + (size_t)(tr * 64 + row) * C + tc * 64 + ks8;
    short8 v;
#pragma unroll
    for (int q = 0; q < 8; ++q) v[q] = (short)f2bf(p[q]);
    *(short8*)(&tile[row][ks8]) = v;
  }
  __syncthreads();
#pragma unroll
  for (int i = 0; i < 2; ++i) {
    int seg = tid + i * 256;
    int cl = seg >> 3, rs8 = (seg & 7) * 8;
    short8 v;
#pragma unroll
    for (int q = 0; q < 8; ++q) v[q] = (short)tile[rs8 + q][cl];
    *(short8*)(dst + (size_t)(tc * 64 + cl) * R + tr * 64 + rs8) = v;
  }
}

// ---------------- x convert: x[b][t][i] fp32 -> xT[t][b][i] bf16
__global__ __launch_bounds__(256) void xconv(
    const float* __restrict__ xs, const float* __restrict__ xl,
    unsigned short* __restrict__ xTs, unsigned short* __restrict__ xTl) {
  int t = blockIdx.x & 127;
  int bc = (blockIdx.x >> 7) & 3;
  int which = blockIdx.x >> 9;
  const float* x = which ? xl : xs;
  unsigned short* xT = which ? xTl : xTs;
  int b0 = bc * 128;
#pragma unroll
  for (int i = 0; i < 8; ++i) {
    int seg = threadIdx.x + i * 256;
    int bl_ = seg >> 4, i8 = (seg & 15) * 8;
    const float* p = x + (size_t)(b0 + bl_) * 16384 + t * 128 + i8;
    short8 v;
#pragma unroll
    for (int q = 0; q < 8; ++q) v[q] = (short)f2bf(p[q]);
    *(short8*)(xT + ((size_t)t * 512 + b0 + bl_) * 128 + i8) = v;
  }
}

// ---------------- persistent dual-LSTM over all 128 steps
// grid 256 = lstm(2) x mb(16: 32 rows) x nb(8: 64 h)
// wave wn owns h-cols [wn*16, wn*16+16) x ALL 4 gates (gate = MFMA acc idx):
// gate math is lane-local — no cross-wave exchange. B-weights, c, bias in regs.
// h exchange: 16B sc0sc1 stores / L2-bypass loads (MALL-coherent); loads are
// issued+waitcnt'd back-to-back (NO code between asm load and waitcnt: the
// compiler must never get a window to spill/reuse pending asm-load dest regs).
__global__ __launch_bounds__(256, 1) void lstm_persistent(
    const unsigned short* __restrict__ xTs, const unsigned short* __restrict__ xTl,
    const unsigned short* __restrict__ WTs, const unsigned short* __restrict__ WTl,
    const float* __restrict__ bs, const float* __restrict__ bl,
    unsigned short* __restrict__ hs0, unsigned short* __restrict__ hs1,
    unsigned short* __restrict__ hl0, unsigned short* __restrict__ hl1,
    int* __restrict__ flags) {
  const int bid = blockIdx.x;
  const int lstm = bid & 1;
  const int mb = (bid >> 1) & 15;
  const int nb = bid >> 5;
  const int grp = lstm * 16 + mb;          // 32 groups x 8 blocks
  const int b0 = mb * 32;
  const int H0 = nb * 64;

  const unsigned short* xT = lstm ? xTl : xTs;
  const unsigned short* WT = lstm ? WTl : WTs;
  const float* bias = lstm ? bl : bs;
  unsigned short* h0 = lstm ? hl0 : hs0;
  unsigned short* h1 = lstm ? hl1 : hs1;

  __shared__ unsigned short As[32][648];   // 41472 B; row stride 1296 B (16B-aligned)
  __shared__ unsigned short hbuf[32][72];  // 4608 B; h repack for 16B global stores

  const int tid = threadIdx.x;
  const int wn = tid >> 6;     // wave = h-subtile
  const int lane = tid & 63;
  const int quad = lane >> 4;
  const int lrow = lane & 15;
  const int colL = wn * 16 + lrow;   // local h col this lane owns

  // bias (4 scalars) + c state (8) in registers
  float bias_r[4];
#pragma unroll
  for (int g = 0; g < 4; ++g) bias_r[g] = bias[g * HD + H0 + colL];
  float c_r[8];
#pragma unroll
  for (int j = 0; j < 8; ++j) c_r[j] = 0.f;

  // B fragments: breg[gate][kc], rows of W^T for (gate, h=H0+colL)
  bf16x8 breg[4][20];
#pragma unroll
  for (int g = 0; g < 4; ++g) {
    const unsigned short* wp = WT + (size_t)(g * HD + H0 + colL) * KD + quad * 8;
#pragma unroll
    for (int kc = 0; kc < 20; ++kc)
      breg[g][kc] = __builtin_bit_cast(bf16x8, *(const short8*)(wp + kc * 32));
  }

  // global-store slice for this thread (from hbuf)
  const int st_row = tid >> 3, st_c8 = (tid & 7) * 8;
  const unsigned long long hstA =
      (unsigned long long)(h1 + (size_t)(b0 + st_row) * HD + H0 + st_c8);  // t even
  const unsigned long long hstB =
      (unsigned long long)(h0 + (size_t)(b0 + st_row) * HD + H0 + st_c8);  // t odd

#pragma unroll 1
  for (int t = 0; t < 128; ++t) {
    const unsigned short* hr = (t & 1) ? h1 : h0;

    // ---- 1. stage x_t into As cols [0,128)
#pragma unroll
    for (int i = 0; i < 2; ++i) {
      int seg = tid + i * 256;
      int row = seg >> 4, ch = seg & 15;
      short8 v = *(const short8*)(xT + ((size_t)t * 512 + b0 + row) * 128 + ch * 8);
      *(short8*)(&As[row][ch * 8]) = v;
    }

    // ---- 2. wait for h(t) flags, then load+land h into As cols [128,640)
    //         (load -> waitcnt -> LDS store back-to-back: no spill window)
    if (t > 0) {
      if (wn == 0) {
        while (true) {
          int v = __hip_atomic_load(flags + grp * 16 + (lane & 7),
                                    __ATOMIC_RELAXED, __HIP_MEMORY_SCOPE_AGENT);
          if (__ballot(v >= t) == 0xFFFFFFFFFFFFFFFFull) break;
          __builtin_amdgcn_s_sleep(1);
        }
      }
      __syncthreads();
      uintx4 hv_[8];
#pragma unroll
      for (int i = 0; i < 8; ++i) {
        int chunk = tid + i * 256;
        int row = chunk >> 6, ch = chunk & 63;
        hv_[i] = load16_cc((unsigned long long)(hr + (size_t)(b0 + row) * HD + ch * 8));
      }
      waitcnt_vm0();
#pragma unroll
      for (int i = 0; i < 8; ++i) {
        int chunk = tid + i * 256;
        int row = chunk >> 6, ch = chunk & 63;
        *(uintx4*)(&As[row][128 + ch * 8]) = hv_[i];
      }
    } else {
#pragma unroll
      for (int i = 0; i < 8; ++i) {
        int chunk = tid + i * 256;
        int row = chunk >> 6, ch = chunk & 63;
        *(uintx4*)(&As[row][128 + ch * 8]) = (uintx4){0, 0, 0, 0};
      }
    }
    __syncthreads();

    // ---- 3. full-K MFMA (20 chunks) off LDS A-frags x register B-frags
    floatx4 acc[2][4];
#pragma unroll
    for (int mt = 0; mt < 2; ++mt)
#pragma unroll
      for (int g = 0; g < 4; ++g) acc[mt][g] = (floatx4){0.f, 0.f, 0.f, 0.f};
#pragma unroll
    for (int kc = 0; kc < 20; ++kc) {
      bf16x8 a0 = __builtin_bit_cast(bf16x8, *(const short8*)(&As[lrow][kc * 32 + quad * 8]));
      bf16x8 a1 = __builtin_bit_cast(bf16x8, *(const short8*)(&As[16 + lrow][kc * 32 + quad * 8]));
#pragma unroll
      for (int g = 0; g < 4; ++g) {
        acc[0][g] = __builtin_amdgcn_mfma_f32_16x16x32_bf16(a0, breg[g][kc], acc[0][g], 0, 0, 0);
        acc[1][g] = __builtin_amdgcn_mfma_f32_16x16x32_bf16(a1, breg[g][kc], acc[1][g], 0, 0, 0);
      }
    }

    // ---- 4. lane-local gate math; h -> hbuf (b16 writes)
#pragma unroll
    for (int mt = 0; mt < 2; ++mt)
#pragma unroll
      for (int r = 0; r < 4; ++r) {
        int j = mt * 4 + r;
        float fg = acc[mt][0][r] + bias_r[0];
        float ig = acc[mt][1][r] + bias_r[1];
        float og = acc[mt][2][r] + bias_r[2];
        float cg = acc[mt][3][r] + bias_r[3];
        float cn = sigmoidf_(fg) * c_r[j] + sigmoidf_(ig) * tanhf_(cg);
        float hn = sigmoidf_(og) * tanhf_(cn);
        c_r[j] = cn;
        hbuf[mt * 16 + quad * 4 + r][colL] = f2bf(hn);
      }
    __syncthreads();

    // ---- 5. coalesced 16B h store to MALL
    {
      short8 hv8 = *(const short8*)(&hbuf[st_row][st_c8]);
      store16_cc((t & 1) ? hstB : hstA, __builtin_bit_cast(uintx4, hv8));
      waitcnt_vm0();
    }
    __syncthreads();   // all h stores drained before flag; hbuf reads done

    if (tid == 0 && t < 127)
      __hip_atomic_store(flags + grp * 16 + nb, t + 1,
                         __ATOMIC_RELAXED, __HIP_MEMORY_SCOPE_AGENT);
  }
}

// ---------------- out = tanh(concat(hs,hl) @ out_W + out_b), fp32 out
__global__ __launch_bounds__(256) void out_gemm(
    const unsigned short* __restrict__ hs, const unsigned short* __restrict__ hl,
    const unsigned short* __restrict__ WTo,  // [512][1024] bf16
    const float* __restrict__ ob, float* __restrict__ out) {
  const int bx = blockIdx.x;
  const int mb = bx & 7;
  const int nb = bx >> 3;

  __shared__ unsigned short As2[64][88];
  __shared__ unsigned short Bs2[128][88];

  const int tid = threadIdx.x;
  const int wave = tid >> 6;
  const int lane = tid & 63;
  const int quad = lane >> 4;
  const int lrow = lane & 15;
  const int wm = wave & 1;
  const int wn = wave >> 1;

  floatx4 acc[8];
#pragma unroll
  for (int i = 0; i < 8; ++i) acc[i] = (floatx4){0.f, 0.f, 0.f, 0.f};

  for (int k0 = 0; k0 < 1024; k0 += 64) {
#pragma unroll
    for (int i = 0; i < 2; ++i) {
      int seg = tid + i * 256;
      int row = seg >> 3, ks8 = (seg & 7) * 8;
      int kg = k0 + ks8;
      int b = mb * 64 + row;
      const unsigned short* src =
          (kg < 512) ? (hs + (size_t)b * HD + kg) : (hl + (size_t)b * HD + (kg - 512));
      *(short8*)(&As2[row][ks8]) = *(const short8*)src;
    }
#pragma unroll
    for (int i = 0; i < 4; ++i) {
      int seg = tid + i * 256;
      int n = seg >> 3, ks8 = (seg & 7) * 8;
      *(short8*)(&Bs2[n][ks8]) =
          *(const short8*)(WTo + (size_t)(nb * 128 + n) * 1024 + k0 + ks8);
    }
    __syncthreads();
#pragma unroll
    for (int ks = 0; ks < 64; ks += 32) {
      int kq = ks + quad * 8;
      bf16x8 a0 = __builtin_bit_cast(bf16x8, *(const short8*)(&As2[wm * 32 + lrow][kq]));
      bf16x8 a1 = __builtin_bit_cast(bf16x8, *(const short8*)(&As2[wm * 32 + 16 + lrow][kq]));
#pragma unroll
      for (int nt = 0; nt < 4; ++nt) {
        bf16x8 bfr = __builtin_bit_cast(bf16x8, *(const short8*)(&Bs2[wn * 64 + nt * 16 + lrow][kq]));
        acc[nt] = __builtin_amdgcn_mfma_f32_16x16x32_bf16(a0, bfr, acc[nt], 0, 0, 0);
        acc[4 + nt] = __builtin_amdgcn_mfma_f32_16x16x32_bf16(a1, bfr, acc[4 + nt], 0, 0, 0);
      }
    }
    __syncthreads();
  }
#pragma unroll
  for (int mt = 0; mt < 2; ++mt) {
#pragma unroll
    for (int nt = 0; nt < 4; ++nt) {
      int n = nb * 128 + wn * 64 + nt * 16 + lrow;
      float bv = ob[n];
#pragma unroll
      for (int r = 0; r < 4; ++r) {
        int b = mb * 64 + wm * 32 + mt * 16 + quad * 4 + r;
        out[(size_t)b * HD + n] = tanhf_(acc[mt * 4 + nt][r] + bv);
      }
    }
  }
}

extern "C" void kernel_launch(void* const* d_in, const int* in_sizes, int n_in,
                              void* d_out, int out_size, void* d_ws, size_t ws_size,
                              hipStream_t stream) {
  (void)in_sizes; (void)n_in; (void)out_size; (void)ws_size;
  const float* xs = (const float*)d_in[0];
  const float* xl = (const float*)d_in[1];
  const float* sW = (const float*)d_in[4];
  const float* sb = (const float*)d_in[5];
  const float* lW = (const float*)d_in[6];
  const float* lb = (const float*)d_in[7];
  const float* oW = (const float*)d_in[8];
  const float* ob = (const float*)d_in[9];

  char* w = (char*)d_ws;
  int* flags = (int*)w;                                 // 32 grp x 16 ints
  unsigned short* WTs = (unsigned short*)(w + 4096);    // [2048][640]
  unsigned short* WTl = WTs + (size_t)G4 * KD;
  unsigned short* WTo = WTl + (size_t)G4 * KD;          // [512][1024]
  unsigned short* xTs = WTo + (size_t)HD * 1024;        // [128][512][128]
  unsigned short* xTl = xTs + (size_t)128 * 512 * 128;
  unsigned short* hs0 = xTl + (size_t)128 * 512 * 128;
  unsigned short* hs1 = hs0 + (size_t)512 * HD;
  unsigned short* hl0 = hs1 + (size_t)512 * HD;
  unsigned short* hl1 = hl0 + (size_t)512 * HD;

  hipMemsetAsync(flags, 0, 4096, stream);
  transpose_f32_bf16<<<(640 / 64) * (2048 / 64), 256, 0, stream>>>(sW, WTs, 640, 2048);
  transpose_f32_bf16<<<(640 / 64) * (2048 / 64), 256, 0, stream>>>(lW, WTl, 640, 2048);
  transpose_f32_bf16<<<(1024 / 64) * (512 / 64), 256, 0, stream>>>(oW, WTo, 1024, 512);
  xconv<<<1024, 256, 0, stream>>>(xs, xl, xTs, xTl);

  const float* sbp = sb; const float* lbp = lb;
  const unsigned short *xTs_c = xTs, *xTl_c = xTl, *WTs_c = WTs, *WTl_c = WTl;
  unsigned short *a_hs0 = hs0, *a_hs1 = hs1, *a_hl0 = hl0, *a_hl1 = hl1;
  int* a_flags = flags;
  void* args[] = {(void*)&xTs_c, (void*)&xTl_c, (void*)&WTs_c, (void*)&WTl_c,
                  (void*)&sbp, (void*)&lbp, (void*)&a_hs0, (void*)&a_hs1,
                  (void*)&a_hl0, (void*)&a_hl1, (void*)&a_flags};
  hipError_t e = hipLaunchCooperativeKernel((const void*)lstm_persistent,
                                            dim3(256), dim3(256), args, 0, stream);
  if (e != hipSuccess) {
    lstm_persistent<<<256, 256, 0, stream>>>(xTs, xTl, WTs, WTl, sb, lb,
                                             hs0, hs1, hl0, hl1, flags);
  }
  // t=127 (odd) wrote h0 buffers
  out_gemm<<<32, 256, 0, stream>>>(hs0, hl0, WTo, ob, (float*)d_out);
}

// Round 8
// 741.519 us; speedup vs baseline: 4.1453x; 1.1580x over previous
//
#include <hip/hip_runtime.h>

// Problem: B=512, T=128, I=128, H=512 (fp32 in/out; bf16 MFMA internally)
#define HD 512
#define KD 640
#define G4 2048

typedef short short8 __attribute__((ext_vector_type(8)));
typedef __bf16 bf16x8 __attribute__((ext_vector_type(8)));
typedef float floatx4 __attribute__((ext_vector_type(4)));
typedef unsigned int uintx4 __attribute__((ext_vector_type(4)));

static __device__ __forceinline__ unsigned short f2bf(float f) {
  unsigned int u = __float_as_uint(f);
  u += 0x7fffu + ((u >> 16) & 1u);   // RNE
  return (unsigned short)(u >> 16);
}
static __device__ __forceinline__ float rcp_(float x) {
  return __builtin_amdgcn_rcpf(x);
}
static __device__ __forceinline__ float sigmoidf_(float x) {
  return rcp_(1.f + __expf(-x));
}
static __device__ __forceinline__ float tanhf_(float x) {
  float ax = fabsf(x);
  float e = __expf(-2.f * ax);
  float r = fmaf(-2.f * e, rcp_(1.f + e), 1.f);
  return copysignf(r, x);
}
// agent-coherent 16B store: sc0 sc1 = write-through to MALL
static __device__ __forceinline__ void store16_cc(unsigned long long a, uintx4 v) {
  asm volatile("global_store_dwordx4 %0, %1, off sc0 sc1" :: "v"(a), "v"(v) : "memory");
}
static __device__ __forceinline__ void waitcnt_vm0() {
  asm volatile("s_waitcnt vmcnt(0)" ::: "memory");
}
// global -> LDS direct DMA, 16B/lane, SC0|SC1 (=17) cache policy: bypass L1/L2,
// read at MALL (coherent with store16_cc). LDS dest = wave-uniform base + lane*16.
static __device__ __forceinline__ void load_lds16_cc(const void* g, void* l) {
  __builtin_amdgcn_global_load_lds(
      (const __attribute__((address_space(1))) void*)(unsigned long long)(uintptr_t)g,
      (__attribute__((address_space(3))) void*)l, 16, 0, 17);
}

// ---------------- transpose + cast: src[R][C] fp32 -> dst[C][R] bf16
__global__ __launch_bounds__(256) void transpose_f32_bf16(
    const float* __restrict__ src, unsigned short* __restrict__ dst,
    int R, int C) {
  __shared__ unsigned short tile[64][80];
  int nR = R >> 6;
  int tr = blockIdx.x % nR;
  int tc = blockIdx.x / nR;
  int tid = threadIdx.x;
#pragma unroll
  for (int i = 0; i < 2; ++i) {
    int seg = tid + i * 256;
    int row = seg >> 3, ks8 = (seg & 7) * 8;
    const float* p = src + (size_t)(tr * 64 + row) * C + tc * 64 + ks8;
    short8 v;
#pragma unroll
    for (int q = 0; q < 8; ++q) v[q] = (short)f2bf(p[q]);
    *(short8*)(&tile[row][ks8]) = v;
  }
  __syncthreads();
#pragma unroll
  for (int i = 0; i < 2; ++i) {
    int seg = tid + i * 256;
    int cl = seg >> 3, rs8 = (seg & 7) * 8;
    short8 v;
#pragma unroll
    for (int q = 0; q < 8; ++q) v[q] = (short)tile[rs8 + q][cl];
    *(short8*)(dst + (size_t)(tc * 64 + cl) * R + tr * 64 + rs8) = v;
  }
}

// ---------------- x convert: x[b][t][i] fp32 -> xT[t][b][i] bf16
__global__ __launch_bounds__(256) void xconv(
    const float* __restrict__ xs, const float* __restrict__ xl,
    unsigned short* __restrict__ xTs, unsigned short* __restrict__ xTl) {
  int t = blockIdx.x & 127;
  int bc = (blockIdx.x >> 7) & 3;
  int which = blockIdx.x >> 9;
  const float* x = which ? xl : xs;
  unsigned short* xT = which ? xTl : xTs;
  int b0 = bc * 128;
#pragma unroll
  for (int i = 0; i < 8; ++i) {
    int seg = threadIdx.x + i * 256;
    int bl_ = seg >> 4, i8 = (seg & 15) * 8;
    const float* p = x + (size_t)(b0 + bl_) * 16384 + t * 128 + i8;
    short8 v;
#pragma unroll
    for (int q = 0; q < 8; ++q) v[q] = (short)f2bf(p[q]);
    *(short8*)(xT + ((size_t)t * 512 + b0 + bl_) * 128 + i8) = v;
  }
}

// ---------------- persistent dual-LSTM over all 128 steps (pipelined)
// grid 256 = lstm(2) x mb(16: 32 rows) x nb(8: 64 h)
// wave wn owns h-cols [wn*16,+16) x ALL 4 gates — gate math lane-local.
// Pipeline per step: poll -> bar -> issue h global_load_lds -> x-MFMA(kc0..3)
// -> vmcnt0 -> bar -> h-MFMA(kc4..19) -> epilogue -> bar -> h store
// -> x(t+1) prefetch under store-ack -> vmcnt0 -> flag post.
__global__ __launch_bounds__(256, 1) void lstm_persistent(
    const unsigned short* __restrict__ xTs, const unsigned short* __restrict__ xTl,
    const unsigned short* __restrict__ WTs, const unsigned short* __restrict__ WTl,
    const float* __restrict__ bs, const float* __restrict__ bl,
    unsigned short* __restrict__ hs0, unsigned short* __restrict__ hs1,
    unsigned short* __restrict__ hl0, unsigned short* __restrict__ hl1,
    int* __restrict__ flags) {
  const int bid = blockIdx.x;
  const int lstm = bid & 1;
  const int mb = (bid >> 1) & 15;
  const int nb = bid >> 5;
  const int grp = lstm * 16 + mb;          // 32 groups x 8 blocks
  const int b0 = mb * 32;
  const int H0 = nb * 64;

  const unsigned short* xT = lstm ? xTl : xTs;
  const unsigned short* WT = lstm ? WTl : WTs;
  const float* bias = lstm ? bl : bs;
  unsigned short* h0 = lstm ? hl0 : hs0;
  unsigned short* h1 = lstm ? hl1 : hs1;

  __shared__ unsigned short As[32][648];   // 41472 B; row stride 1296 B
  __shared__ unsigned short hbuf[32][72];  // 4608 B

  const int tid = threadIdx.x;
  const int wn = tid >> 6;
  const int lane = tid & 63;
  const int quad = lane >> 4;
  const int lrow = lane & 15;
  const int colL = wn * 16 + lrow;

  float bias_r[4];
#pragma unroll
  for (int g = 0; g < 4; ++g) bias_r[g] = bias[g * HD + H0 + colL];
  float c_r[8];
#pragma unroll
  for (int j = 0; j < 8; ++j) c_r[j] = 0.f;

  bf16x8 breg[4][20];
#pragma unroll
  for (int g = 0; g < 4; ++g) {
    const unsigned short* wp = WT + (size_t)(g * HD + H0 + colL) * KD + quad * 8;
#pragma unroll
    for (int kc = 0; kc < 20; ++kc)
      breg[g][kc] = __builtin_bit_cast(bf16x8, *(const short8*)(wp + kc * 32));
  }

  const int st_row = tid >> 3, st_c8 = (tid & 7) * 8;
  const unsigned long long hstA =
      (unsigned long long)(h1 + (size_t)(b0 + st_row) * HD + H0 + st_c8);  // t even
  const unsigned long long hstB =
      (unsigned long long)(h0 + (size_t)(b0 + st_row) * HD + H0 + st_c8);  // t odd

  // ---- prologue: stage x(0); zero h-part of As
#pragma unroll
  for (int i = 0; i < 2; ++i) {
    int seg = tid + i * 256;
    int row = seg >> 4, ch = seg & 15;
    short8 v = *(const short8*)(xT + ((size_t)(b0 + row)) * 128 + ch * 8);  // t=0
    *(short8*)(&As[row][ch * 8]) = v;
  }
#pragma unroll
  for (int i = 0; i < 8; ++i) {
    int chunk = tid + i * 256;
    int row = chunk >> 6, ch = chunk & 63;
    *(uintx4*)(&As[row][128 + ch * 8]) = (uintx4){0, 0, 0, 0};
  }

#pragma unroll 1
  for (int t = 0; t < 128; ++t) {
    const unsigned short* hr = (t & 1) ? h1 : h0;

    // (A) poll flags for h(t)
    if (t > 0 && wn == 0) {
      while (true) {
        int v = __hip_atomic_load(flags + grp * 16 + (lane & 7),
                                  __ATOMIC_RELAXED, __HIP_MEMORY_SCOPE_AGENT);
        if (__ballot(v >= t) == 0xFFFFFFFFFFFFFFFFull) break;
        __builtin_amdgcn_s_sleep(1);
      }
    }
    __syncthreads();   // (B) x(t) staged (prev tail) visible; flags passed

    // (C) issue h(t) -> LDS direct DMA (wave-uniform row per iteration)
    if (t > 0) {
#pragma unroll
      for (int i = 0; i < 8; ++i) {
        int row = wn + i * 4;  // (wn*64 + i*256) >> 6
        load_lds16_cc(hr + (size_t)(b0 + row) * HD + lane * 8, &As[row][128]);
      }
    }

    // (D) x-part MFMA (kc 0..3) while h loads are in flight
    floatx4 acc[2][4];
#pragma unroll
    for (int mt = 0; mt < 2; ++mt)
#pragma unroll
      for (int g = 0; g < 4; ++g) acc[mt][g] = (floatx4){0.f, 0.f, 0.f, 0.f};
#pragma unroll
    for (int kc = 0; kc < 4; ++kc) {
      bf16x8 a0 = __builtin_bit_cast(bf16x8, *(const short8*)(&As[lrow][kc * 32 + quad * 8]));
      bf16x8 a1 = __builtin_bit_cast(bf16x8, *(const short8*)(&As[16 + lrow][kc * 32 + quad * 8]));
#pragma unroll
      for (int g = 0; g < 4; ++g) {
        acc[0][g] = __builtin_amdgcn_mfma_f32_16x16x32_bf16(a0, breg[g][kc], acc[0][g], 0, 0, 0);
        acc[1][g] = __builtin_amdgcn_mfma_f32_16x16x32_bf16(a1, breg[g][kc], acc[1][g], 0, 0, 0);
      }
    }

    waitcnt_vm0();     // (E) h landed in LDS
    __syncthreads();   // (F) all waves' h landed

    // (G) h-part MFMA (kc 4..19)
#pragma unroll
    for (int kc = 4; kc < 20; ++kc) {
      bf16x8 a0 = __builtin_bit_cast(bf16x8, *(const short8*)(&As[lrow][kc * 32 + quad * 8]));
      bf16x8 a1 = __builtin_bit_cast(bf16x8, *(const short8*)(&As[16 + lrow][kc * 32 + quad * 8]));
#pragma unroll
      for (int g = 0; g < 4; ++g) {
        acc[0][g] = __builtin_amdgcn_mfma_f32_16x16x32_bf16(a0, breg[g][kc], acc[0][g], 0, 0, 0);
        acc[1][g] = __builtin_amdgcn_mfma_f32_16x16x32_bf16(a1, breg[g][kc], acc[1][g], 0, 0, 0);
      }
    }

    // (H) lane-local gate math -> hbuf
#pragma unroll
    for (int mt = 0; mt < 2; ++mt)
#pragma unroll
      for (int r = 0; r < 4; ++r) {
        int j = mt * 4 + r;
        float fg = acc[mt][0][r] + bias_r[0];
        float ig = acc[mt][1][r] + bias_r[1];
        float og = acc[mt][2][r] + bias_r[2];
        float cg = acc[mt][3][r] + bias_r[3];
        float cn = sigmoidf_(fg) * c_r[j] + sigmoidf_(ig) * tanhf_(cg);
        float hn = sigmoidf_(og) * tanhf_(cn);
        c_r[j] = cn;
        hbuf[mt * 16 + quad * 4 + r][colL] = f2bf(hn);
      }
    __syncthreads();   // (I) hbuf complete; all waves past MFMA reads of As

    // (J) h(t+1) store to MALL
    short8 hv8 = *(const short8*)(&hbuf[st_row][st_c8]);
    store16_cc((t & 1) ? hstB : hstA, __builtin_bit_cast(uintx4, hv8));

    // (K1) prefetch x(t+1) while the store ack is in flight
    short8 xv[2];
    if (t < 127) {
#pragma unroll
      for (int i = 0; i < 2; ++i) {
        int seg = tid + i * 256;
        int row = seg >> 4, ch = seg & 15;
        xv[i] = *(const short8*)(xT + ((size_t)(t + 1) * 512 + b0 + row) * 128 + ch * 8);
      }
    }
    waitcnt_vm0();     // (L) h store ack'd + x prefetch data in VGPRs
    if (t < 127) {
#pragma unroll
      for (int i = 0; i < 2; ++i) {   // (K2) land x(t+1)
        int seg = tid + i * 256;
        int row = seg >> 4, ch = seg & 15;
        *(short8*)(&As[row][ch * 8]) = xv[i];
      }
      if (tid == 0)                    // (M) publish
        __hip_atomic_store(flags + grp * 16 + nb, t + 1,
                           __ATOMIC_RELAXED, __HIP_MEMORY_SCOPE_AGENT);
    }
  }
}

// ---------------- out = tanh(concat(hs,hl) @ out_W + out_b), fp32 out
__global__ __launch_bounds__(256) void out_gemm(
    const unsigned short* __restrict__ hs, const unsigned short* __restrict__ hl,
    const unsigned short* __restrict__ WTo,  // [512][1024] bf16
    const float* __restrict__ ob, float* __restrict__ out) {
  const int bx = blockIdx.x;
  const int mb = bx & 7;
  const int nb = bx >> 3;

  __shared__ unsigned short As2[64][88];
  __shared__ unsigned short Bs2[128][88];

  const int tid = threadIdx.x;
  const int wave = tid >> 6;
  const int lane = tid & 63;
  const int quad = lane >> 4;
  const int lrow = lane & 15;
  const int wm = wave & 1;
  const int wn = wave >> 1;

  floatx4 acc[8];
#pragma unroll
  for (int i = 0; i < 8; ++i) acc[i] = (floatx4){0.f, 0.f, 0.f, 0.f};

  for (int k0 = 0; k0 < 1024; k0 += 64) {
#pragma unroll
    for (int i = 0; i < 2; ++i) {
      int seg = tid + i * 256;
      int row = seg >> 3, ks8 = (seg & 7) * 8;
      int kg = k0 + ks8;
      int b = mb * 64 + row;
      const unsigned short* src =
          (kg < 512) ? (hs + (size_t)b * HD + kg) : (hl + (size_t)b * HD + (kg - 512));
      *(short8*)(&As2[row][ks8]) = *(const short8*)src;
    }
#pragma unroll
    for (int i = 0; i < 4; ++i) {
      int seg = tid + i * 256;
      int n = seg >> 3, ks8 = (seg & 7) * 8;
      *(short8*)(&Bs2[n][ks8]) =
          *(const short8*)(WTo + (size_t)(nb * 128 + n) * 1024 + k0 + ks8);
    }
    __syncthreads();
#pragma unroll
    for (int ks = 0; ks < 64; ks += 32) {
      int kq = ks + quad * 8;
      bf16x8 a0 = __builtin_bit_cast(bf16x8, *(const short8*)(&As2[wm * 32 + lrow][kq]));
      bf16x8 a1 = __builtin_bit_cast(bf16x8, *(const short8*)(&As2[wm * 32 + 16 + lrow][kq]));
#pragma unroll
      for (int nt = 0; nt < 4; ++nt) {
        bf16x8 bfr = __builtin_bit_cast(bf16x8, *(const short8*)(&Bs2[wn * 64 + nt * 16 + lrow][kq]));
        acc[nt] = __builtin_amdgcn_mfma_f32_16x16x32_bf16(a0, bfr, acc[nt], 0, 0, 0);
        acc[4 + nt] = __builtin_amdgcn_mfma_f32_16x16x32_bf16(a1, bfr, acc[4 + nt], 0, 0, 0);
      }
    }
    __syncthreads();
  }
#pragma unroll
  for (int mt = 0; mt < 2; ++mt) {
#pragma unroll
    for (int nt = 0; nt < 4; ++nt) {
      int n = nb * 128 + wn * 64 + nt * 16 + lrow;
      float bv = ob[n];
#pragma unroll
      for (int r = 0; r < 4; ++r) {
        int b = mb * 64 + wm * 32 + mt * 16 + quad * 4 + r;
        out[(size_t)b * HD + n] = tanhf_(acc[mt * 4 + nt][r] + bv);
      }
    }
  }
}

extern "C" void kernel_launch(void* const* d_in, const int* in_sizes, int n_in,
                              void* d_out, int out_size, void* d_ws, size_t ws_size,
                              hipStream_t stream) {
  (void)in_sizes; (void)n_in; (void)out_size; (void)ws_size;
  const float* xs = (const float*)d_in[0];
  const float* xl = (const float*)d_in[1];
  const float* sW = (const float*)d_in[4];
  const float* sb = (const float*)d_in[5];
  const float* lW = (const float*)d_in[6];
  const float* lb = (const float*)d_in[7];
  const float* oW = (const float*)d_in[8];
  const float* ob = (const float*)d_in[9];

  char* w = (char*)d_ws;
  int* flags = (int*)w;                                 // 32 grp x 16 ints
  unsigned short* WTs = (unsigned short*)(w + 4096);    // [2048][640]
  unsigned short* WTl = WTs + (size_t)G4 * KD;
  unsigned short* WTo = WTl + (size_t)G4 * KD;          // [512][1024]
  unsigned short* xTs = WTo + (size_t)HD * 1024;        // [128][512][128]
  unsigned short* xTl = xTs + (size_t)128 * 512 * 128;
  unsigned short* hs0 = xTl + (size_t)128 * 512 * 128;
  unsigned short* hs1 = hs0 + (size_t)512 * HD;
  unsigned short* hl0 = hs1 + (size_t)512 * HD;
  unsigned short* hl1 = hl0 + (size_t)512 * HD;

  hipMemsetAsync(flags, 0, 4096, stream);
  transpose_f32_bf16<<<(640 / 64) * (2048 / 64), 256, 0, stream>>>(sW, WTs, 640, 2048);
  transpose_f32_bf16<<<(640 / 64) * (2048 / 64), 256, 0, stream>>>(lW, WTl, 640, 2048);
  transpose_f32_bf16<<<(1024 / 64) * (512 / 64), 256, 0, stream>>>(oW, WTo, 1024, 512);
  xconv<<<1024, 256, 0, stream>>>(xs, xl, xTs, xTl);

  const float* sbp = sb; const float* lbp = lb;
  const unsigned short *xTs_c = xTs, *xTl_c = xTl, *WTs_c = WTs, *WTl_c = WTl;
  unsigned short *a_hs0 = hs0, *a_hs1 = hs1, *a_hl0 = hl0, *a_hl1 = hl1;
  int* a_flags = flags;
  void* args[] = {(void*)&xTs_c, (void*)&xTl_c, (void*)&WTs_c, (void*)&WTl_c,
                  (void*)&sbp, (void*)&lbp, (void*)&a_hs0, (void*)&a_hs1,
                  (void*)&a_hl0, (void*)&a_hl1, (void*)&a_flags};
  hipError_t e = hipLaunchCooperativeKernel((const void*)lstm_persistent,
                                            dim3(256), dim3(256), args, 0, stream);
  if (e != hipSuccess) {
    lstm_persistent<<<256, 256, 0, stream>>>(xTs, xTl, WTs, WTl, sb, lb,
                                             hs0, hs1, hl0, hl1, flags);
  }
  // t=127 (odd) wrote h0 buffers
  out_gemm<<<32, 256, 0, stream>>>(hs0, hl0, WTo, ob, (float*)d_out);
}